// Round 2
// baseline (1545.063 us; speedup 1.0000x reference)
//
#include <hip/hip_runtime.h>

// Reference computation:
//   deg[i]   = # edges with col==i
//   dis[i]   = deg>0 ? rsqrt(deg) : 0
//   agg[c]   = sum over edges (r,c) of dis[r]*dis[c]*x[r]
//            = dis[c] * sum over edges (r,c) of (dis[r]*x[r])   <-- factored!
//   z[i]     = x[i]*nw[i] + agg[i] + bias
//   out[p]   = sign(sigmoid(z[home])-sigmoid(z[away])) == sign(z[home]-z[away])
// (sigmoid strictly monotonic -> skip it; bias kept for fidelity.)

// count in-degree at col
__global__ void k_degree(const int* __restrict__ col, int* __restrict__ deg, int e4) {
    int i = blockIdx.x * blockDim.x + threadIdx.x;
    int stride = gridDim.x * blockDim.x;
    const int4* c4 = (const int4*)col;
    for (; i < e4; i += stride) {
        int4 c = c4[i];
        atomicAdd(&deg[c.x], 1);
        atomicAdd(&deg[c.y], 1);
        atomicAdd(&deg[c.z], 1);
        atomicAdd(&deg[c.w], 1);
    }
}

// dis[i] = deg>0 ? rsqrt(deg) : 0 (written in-place over deg as float)
// px[i]  = dis[i] * x[i]
__global__ void k_dis(int* __restrict__ degdis, const float* __restrict__ x,
                      float* __restrict__ px, int n) {
    int i = blockIdx.x * blockDim.x + threadIdx.x;
    int stride = gridDim.x * blockDim.x;
    float* disf = (float*)degdis;
    for (; i < n; i += stride) {
        int d = degdis[i];
        float v = (d > 0) ? rsqrtf((float)d) : 0.0f;
        disf[i] = v;
        px[i] = v * x[i];
    }
}

// agg[c] += px[r]  (dis[c] factored out, applied in k_z)
__global__ void k_scatter(const int* __restrict__ row, const int* __restrict__ col,
                          const float* __restrict__ px, float* __restrict__ agg, int e4) {
    int i = blockIdx.x * blockDim.x + threadIdx.x;
    int stride = gridDim.x * blockDim.x;
    const int4* r4 = (const int4*)row;
    const int4* c4 = (const int4*)col;
    for (; i < e4; i += stride) {
        int4 r = r4[i];
        int4 c = c4[i];
        atomicAdd(&agg[c.x], px[r.x]);
        atomicAdd(&agg[c.y], px[r.y]);
        atomicAdd(&agg[c.z], px[r.z]);
        atomicAdd(&agg[c.w], px[r.w]);
    }
}

// z[i] = x[i]*nw[i] + dis[i]*agg[i] + bias   (in-place over agg)
__global__ void k_z(const float* __restrict__ x, const float* __restrict__ nw,
                    const float* __restrict__ dis, const float* __restrict__ bias,
                    float* __restrict__ agg, int n) {
    int i = blockIdx.x * blockDim.x + threadIdx.x;
    int stride = gridDim.x * blockDim.x;
    float b = bias[0];
    for (; i < n; i += stride) {
        agg[i] = fmaf(x[i], nw[i], fmaf(dis[i], agg[i], b));
    }
}

__global__ void k_pairs(const float* __restrict__ z, const int* __restrict__ home,
                        const int* __restrict__ away, float* __restrict__ out, int n) {
    int i = blockIdx.x * blockDim.x + threadIdx.x;
    if (i < n) {
        float d = z[home[i]] - z[away[i]];
        out[i] = (d > 0.0f) ? 1.0f : ((d < 0.0f) ? -1.0f : 0.0f);
    }
}

extern "C" void kernel_launch(void* const* d_in, const int* in_sizes, int n_in,
                              void* d_out, int out_size, void* d_ws, size_t ws_size,
                              hipStream_t stream) {
    const float* x    = (const float*)d_in[0];
    const float* nw   = (const float*)d_in[1];
    const float* bias = (const float*)d_in[2];
    const int*   ei   = (const int*)d_in[3];
    const int*   home = (const int*)d_in[4];
    const int*   away = (const int*)d_in[5];
    float* out = (float*)d_out;

    const int N = in_sizes[0];          // 500000
    const int E = in_sizes[3] / 2;      // 16000000
    const int P = in_sizes[4];          // 100000

    const int* row = ei;
    const int* col = ei + E;

    // workspace layout: [deg/dis: N][agg: N][px: N], 256B-aligned slots
    size_t slot = ((size_t)N * 4 + 255) & ~(size_t)255;
    int*   deg = (int*)d_ws;                       // becomes dis (float) in-place
    float* agg = (float*)((char*)d_ws + slot);
    float* px  = (float*)((char*)d_ws + 2 * slot);

    const int T = 256;
    const int gridN = 2048;            // grid-stride over nodes
    const int gridE = 2048;            // grid-stride over edges (int4 chunks)
    const int e4 = E / 4;              // 16M % 4 == 0

    hipMemsetAsync(d_ws, 0, 2 * slot, stream);   // zero deg + agg in one call
    k_degree<<<gridE, T, 0, stream>>>(col, deg, e4);
    k_dis<<<gridN, T, 0, stream>>>(deg, x, px, N);
    k_scatter<<<gridE, T, 0, stream>>>(row, col, px, agg, e4);
    k_z<<<gridN, T, 0, stream>>>(x, nw, (const float*)deg, bias, agg, N);
    k_pairs<<<(P + T - 1) / T, T, 0, stream>>>(agg, home, away, out, P);
}

// Round 3
// 1542.465 us; speedup vs baseline: 1.0017x; 1.0017x over previous
//
#include <hip/hip_runtime.h>

// Reference computation:
//   deg[i] = # edges with col==i
//   dis[i] = deg>0 ? rsqrt(deg) : 0
//   agg[c] = dis[c] * sum over edges (r,c) of (dis[r]*x[r])   (dis[c] factored out)
//   z[i]   = x[i]*nw[i] + agg[i] + bias
//   out[p] = sign(z[home]-z[away])     (sigmoid monotonic -> dropped)
//
// Round-3 theory: device-scope atomics write through to the fabric
// (observed: 500 MB WRITE_SIZE = 16M x 32B for the scatter). Fix: per-XCD
// privatized buffers + WORKGROUP-scope atomics, which execute at the local
// TCC (L2) with no fabric write-through. Copies are merged by a follow-up
// kernel; the implicit L2 writeback at kernel end makes them visible.

#define NCOPY 8   // one copy per XCD

__device__ __forceinline__ int xcd_id() {
    int x;
    asm("s_getreg_b32 %0, hwreg(HW_REG_XCC_ID)" : "=s"(x));
    return x & (NCOPY - 1);
}

// ---------------- fast path: per-XCD privatized, workgroup-scope atomics ----

__global__ void k_degree8(const int* __restrict__ col, unsigned int* __restrict__ deg8,
                          int e4, int N) {
    unsigned int* mydeg = deg8 + (size_t)xcd_id() * N;
    int i = blockIdx.x * blockDim.x + threadIdx.x;
    int stride = gridDim.x * blockDim.x;
    const int4* c4 = (const int4*)col;
    for (; i < e4; i += stride) {
        int4 c = c4[i];
        __hip_atomic_fetch_add(&mydeg[c.x], 1u, __ATOMIC_RELAXED, __HIP_MEMORY_SCOPE_WORKGROUP);
        __hip_atomic_fetch_add(&mydeg[c.y], 1u, __ATOMIC_RELAXED, __HIP_MEMORY_SCOPE_WORKGROUP);
        __hip_atomic_fetch_add(&mydeg[c.z], 1u, __ATOMIC_RELAXED, __HIP_MEMORY_SCOPE_WORKGROUP);
        __hip_atomic_fetch_add(&mydeg[c.w], 1u, __ATOMIC_RELAXED, __HIP_MEMORY_SCOPE_WORKGROUP);
    }
}

// dis[i] = rsqrt(sum of 8 deg copies), px[i] = dis[i]*x[i]
__global__ void k_dis8(const unsigned int* __restrict__ deg8, const float* __restrict__ x,
                       float* __restrict__ dis, float* __restrict__ px, int n, int N) {
    int i = blockIdx.x * blockDim.x + threadIdx.x;
    int stride = gridDim.x * blockDim.x;
    for (; i < n; i += stride) {
        unsigned int d = 0;
        #pragma unroll
        for (int k = 0; k < NCOPY; ++k) d += deg8[(size_t)k * N + i];
        float v = (d > 0u) ? rsqrtf((float)d) : 0.0f;
        dis[i] = v;
        px[i] = v * x[i];
    }
}

__global__ void k_scatter8(const int* __restrict__ row, const int* __restrict__ col,
                           const float* __restrict__ px, float* __restrict__ agg8,
                           int e4, int N) {
    float* myagg = agg8 + (size_t)xcd_id() * N;
    int i = blockIdx.x * blockDim.x + threadIdx.x;
    int stride = gridDim.x * blockDim.x;
    const int4* r4 = (const int4*)row;
    const int4* c4 = (const int4*)col;
    for (; i < e4; i += stride) {
        int4 r = r4[i];
        int4 c = c4[i];
        __hip_atomic_fetch_add(&myagg[c.x], px[r.x], __ATOMIC_RELAXED, __HIP_MEMORY_SCOPE_WORKGROUP);
        __hip_atomic_fetch_add(&myagg[c.y], px[r.y], __ATOMIC_RELAXED, __HIP_MEMORY_SCOPE_WORKGROUP);
        __hip_atomic_fetch_add(&myagg[c.z], px[r.z], __ATOMIC_RELAXED, __HIP_MEMORY_SCOPE_WORKGROUP);
        __hip_atomic_fetch_add(&myagg[c.w], px[r.w], __ATOMIC_RELAXED, __HIP_MEMORY_SCOPE_WORKGROUP);
    }
}

// z[i] = x*nw + dis*sum(agg copies) + bias   (written to z)
__global__ void k_z8(const float* __restrict__ agg8, const float* __restrict__ x,
                     const float* __restrict__ nw, const float* __restrict__ dis,
                     const float* __restrict__ bias, float* __restrict__ z, int n, int N) {
    int i = blockIdx.x * blockDim.x + threadIdx.x;
    int stride = gridDim.x * blockDim.x;
    float b = bias[0];
    for (; i < n; i += stride) {
        float s = 0.0f;
        #pragma unroll
        for (int k = 0; k < NCOPY; ++k) s += agg8[(size_t)k * N + i];
        z[i] = fmaf(x[i], nw[i], fmaf(dis[i], s, b));
    }
}

// ---------------- fallback path: device-scope atomics, single copy ----------

__global__ void k_degree(const int* __restrict__ col, int* __restrict__ deg, int e4) {
    int i = blockIdx.x * blockDim.x + threadIdx.x;
    int stride = gridDim.x * blockDim.x;
    const int4* c4 = (const int4*)col;
    for (; i < e4; i += stride) {
        int4 c = c4[i];
        atomicAdd(&deg[c.x], 1); atomicAdd(&deg[c.y], 1);
        atomicAdd(&deg[c.z], 1); atomicAdd(&deg[c.w], 1);
    }
}

__global__ void k_dis(int* __restrict__ degdis, const float* __restrict__ x,
                      float* __restrict__ px, int n) {
    int i = blockIdx.x * blockDim.x + threadIdx.x;
    int stride = gridDim.x * blockDim.x;
    float* disf = (float*)degdis;
    for (; i < n; i += stride) {
        int d = degdis[i];
        float v = (d > 0) ? rsqrtf((float)d) : 0.0f;
        disf[i] = v;
        px[i] = v * x[i];
    }
}

__global__ void k_scatter(const int* __restrict__ row, const int* __restrict__ col,
                          const float* __restrict__ px, float* __restrict__ agg, int e4) {
    int i = blockIdx.x * blockDim.x + threadIdx.x;
    int stride = gridDim.x * blockDim.x;
    const int4* r4 = (const int4*)row;
    const int4* c4 = (const int4*)col;
    for (; i < e4; i += stride) {
        int4 r = r4[i];
        int4 c = c4[i];
        atomicAdd(&agg[c.x], px[r.x]); atomicAdd(&agg[c.y], px[r.y]);
        atomicAdd(&agg[c.z], px[r.z]); atomicAdd(&agg[c.w], px[r.w]);
    }
}

__global__ void k_z(const float* __restrict__ x, const float* __restrict__ nw,
                    const float* __restrict__ dis, const float* __restrict__ bias,
                    float* __restrict__ agg, int n) {
    int i = blockIdx.x * blockDim.x + threadIdx.x;
    int stride = gridDim.x * blockDim.x;
    float b = bias[0];
    for (; i < n; i += stride) {
        agg[i] = fmaf(x[i], nw[i], fmaf(dis[i], agg[i], b));
    }
}

// ---------------- shared epilogue ------------------------------------------

__global__ void k_pairs(const float* __restrict__ z, const int* __restrict__ home,
                        const int* __restrict__ away, float* __restrict__ out, int n) {
    int i = blockIdx.x * blockDim.x + threadIdx.x;
    if (i < n) {
        float d = z[home[i]] - z[away[i]];
        out[i] = (d > 0.0f) ? 1.0f : ((d < 0.0f) ? -1.0f : 0.0f);
    }
}

extern "C" void kernel_launch(void* const* d_in, const int* in_sizes, int n_in,
                              void* d_out, int out_size, void* d_ws, size_t ws_size,
                              hipStream_t stream) {
    const float* x    = (const float*)d_in[0];
    const float* nw   = (const float*)d_in[1];
    const float* bias = (const float*)d_in[2];
    const int*   ei   = (const int*)d_in[3];
    const int*   home = (const int*)d_in[4];
    const int*   away = (const int*)d_in[5];
    float* out = (float*)d_out;

    const int N = in_sizes[0];          // 500000
    const int E = in_sizes[3] / 2;      // 16000000
    const int P = in_sizes[4];          // 100000

    const int* row = ei;
    const int* col = ei + E;

    const int T = 256;
    const int gridN = 2048;
    const int gridE = 2048;
    const int e4 = E / 4;               // 16M % 4 == 0

    size_t slot = ((size_t)N * 4 + 255) & ~(size_t)255;
    size_t need_fast = (size_t)(NCOPY + 3) * slot;   // copies + dis + px + z

    if (ws_size >= need_fast) {
        // fast path: per-XCD privatized buffers, workgroup-scope atomics
        char* base = (char*)d_ws;
        unsigned int* copies = (unsigned int*)base;               // NCOPY*slot (deg8, then agg8)
        float* dis = (float*)(base + (size_t)NCOPY * slot);
        float* px  = (float*)(base + (size_t)(NCOPY + 1) * slot);
        float* z   = (float*)(base + (size_t)(NCOPY + 2) * slot);

        hipMemsetAsync(copies, 0, (size_t)NCOPY * slot, stream);           // deg8 = 0
        k_degree8<<<gridE, T, 0, stream>>>(col, copies, e4, N);
        k_dis8<<<gridN, T, 0, stream>>>(copies, x, dis, px, N, N);
        hipMemsetAsync(copies, 0, (size_t)NCOPY * slot, stream);           // agg8 = 0
        k_scatter8<<<gridE, T, 0, stream>>>(row, col, px, (float*)copies, e4, N);
        k_z8<<<gridN, T, 0, stream>>>((const float*)copies, x, nw, dis, bias, z, N, N);
        k_pairs<<<(P + T - 1) / T, T, 0, stream>>>(z, home, away, out, P);
    } else {
        // fallback: device-scope atomics (round-2 behavior)
        int*   deg = (int*)d_ws;                       // becomes dis in-place
        float* agg = (float*)((char*)d_ws + slot);
        float* px  = (float*)((char*)d_ws + 2 * slot);

        hipMemsetAsync(d_ws, 0, 2 * slot, stream);
        k_degree<<<gridE, T, 0, stream>>>(col, deg, e4);
        k_dis<<<gridN, T, 0, stream>>>(deg, x, px, N);
        k_scatter<<<gridE, T, 0, stream>>>(row, col, px, agg, e4);
        k_z<<<gridN, T, 0, stream>>>(x, nw, (const float*)deg, bias, agg, N);
        k_pairs<<<(P + T - 1) / T, T, 0, stream>>>(agg, home, away, out, P);
    }
}

// Round 4
// 754.937 us; speedup vs baseline: 2.0466x; 2.0432x over previous
//
#include <hip/hip_runtime.h>

// Reference:
//   deg[i] = # edges with col==i ; dis[i] = deg>0 ? rsqrt(deg) : 0
//   agg[c] = dis[c] * sum_{(r,c)} dis[r]*x[r]        (dis[c] factored out)
//   z[i]   = x[i]*nw[i] + agg[i] + bias
//   out[p] = sign(z[home]-z[away])                   (sigmoid monotonic -> dropped)
//
// Round-4: global atomics write through to memory (measured: 32B per atomic,
// ~21G atomics/s, scope qualifier irrelevant). Replace both histogram passes
// with a bucket-sort pipeline using ONLY LDS atomics:
//   hist -> scan -> bin(c16,r32 bucket-sorted) -> LDS degree -> dis/px ->
//   LDS scatter+fused z -> pairs.

#define NPB_SHIFT 11
#define NPB       2048          // nodes per bucket
#define NBMAX     256           // max buckets (N <= 524288)
#define GB        1024          // blocks in edge passes
#define TEDGE     256           // threads in edge passes
#define TBKT      512           // threads in per-bucket passes

// ---- block-wide exclusive scan helpers (blockDim == 256) -------------------

__device__ __forceinline__ unsigned wave_incl_scan(unsigned v) {
    #pragma unroll
    for (int d = 1; d < 64; d <<= 1) {
        unsigned n = __shfl_up((int)v, d, 64);
        if ((threadIdx.x & 63) >= (unsigned)d) v += n;
    }
    return v;
}

__device__ __forceinline__ unsigned block_excl_scan256(unsigned v, unsigned* lds,
                                                       unsigned* total) {
    int lane = threadIdx.x & 63, w = threadIdx.x >> 6;
    unsigned incl = wave_incl_scan(v);
    if (lane == 63) lds[w] = incl;
    __syncthreads();
    if (threadIdx.x == 0) {
        unsigned run = 0;
        #pragma unroll
        for (int i = 0; i < 4; ++i) { unsigned t = lds[i]; lds[i] = run; run += t; }
        lds[4] = run;
    }
    __syncthreads();
    unsigned e = incl - v + lds[w];
    *total = lds[4];
    __syncthreads();
    return e;
}

// ---- pipeline kernels ------------------------------------------------------

// counts[b*GB + blk] = # edges in block blk with bucket b
__global__ __launch_bounds__(TEDGE) void k_hist(const int* __restrict__ col,
                                                unsigned* __restrict__ counts,
                                                int E, int cpb, int NB) {
    __shared__ unsigned hist[NBMAX];
    for (int b = threadIdx.x; b < NBMAX; b += TEDGE) hist[b] = 0;
    __syncthreads();
    int start = blockIdx.x * cpb;
    int end = min(E, start + cpb);
    for (int e = start + threadIdx.x; e < end; e += TEDGE)
        atomicAdd(&hist[((unsigned)col[e]) >> NPB_SHIFT], 1u);
    __syncthreads();
    for (int b = threadIdx.x; b < NB; b += TEDGE)
        counts[(size_t)b * GB + blockIdx.x] = hist[b];
}

// scan each bucket-row of counts in place; rowsum[b] = row total
__global__ __launch_bounds__(256) void k_scanA(unsigned* __restrict__ counts,
                                               unsigned* __restrict__ rowsum) {
    __shared__ unsigned lds[8];
    unsigned carry = 0;
    #pragma unroll
    for (int ch = 0; ch < GB / 256; ++ch) {
        size_t idx = (size_t)blockIdx.x * GB + ch * 256 + threadIdx.x;
        unsigned v = counts[idx];
        unsigned tot;
        unsigned e = block_excl_scan256(v, lds, &tot);
        counts[idx] = e + carry;
        carry += tot;
    }
    if (threadIdx.x == 0) rowsum[blockIdx.x] = carry;
}

// rowbase = exclusive scan of rowsum (NB <= 256, one block)
__global__ __launch_bounds__(256) void k_scanB(const unsigned* __restrict__ rowsum,
                                               unsigned* __restrict__ rowbase, int NB) {
    __shared__ unsigned lds[8];
    unsigned v = (threadIdx.x < (unsigned)NB) ? rowsum[threadIdx.x] : 0u;
    unsigned tot;
    unsigned e = block_excl_scan256(v, lds, &tot);
    if (threadIdx.x < (unsigned)NB) rowbase[threadIdx.x] = e;
}

// write bucket-sorted (c_rel u16, r u32) using exact per-(block,bin) cursors
__global__ __launch_bounds__(TEDGE) void k_bin(const int* __restrict__ row,
                                               const int* __restrict__ col,
                                               const unsigned* __restrict__ counts,
                                               const unsigned* __restrict__ rowbase,
                                               unsigned short* __restrict__ c16,
                                               unsigned* __restrict__ r32,
                                               int E, int cpb, int NB) {
    __shared__ unsigned ofs[NBMAX];
    for (int b = threadIdx.x; b < NB; b += TEDGE)
        ofs[b] = counts[(size_t)b * GB + blockIdx.x] + rowbase[b];
    __syncthreads();
    int start = blockIdx.x * cpb;
    int end = min(E, start + cpb);
    for (int e = start + threadIdx.x; e < end; e += TEDGE) {
        unsigned c = (unsigned)col[e];
        unsigned r = (unsigned)row[e];
        unsigned b = c >> NPB_SHIFT;
        unsigned pos = atomicAdd(&ofs[b], 1u);   // LDS cursor
        c16[pos] = (unsigned short)(c & (NPB - 1));
        r32[pos] = r;
    }
}

// per-bucket degree via LDS counters; non-atomic coalesced deg write
__global__ __launch_bounds__(TBKT) void k_deg(const unsigned short* __restrict__ c16,
                                              const unsigned* __restrict__ rowbase,
                                              unsigned* __restrict__ deg,
                                              int E, int N, int NB) {
    __shared__ unsigned cnt[NPB];
    for (int j = threadIdx.x; j < NPB; j += TBKT) cnt[j] = 0;
    __syncthreads();
    int b = blockIdx.x;
    unsigned base = rowbase[b];
    unsigned end = (b == NB - 1) ? (unsigned)E : rowbase[b + 1];
    for (unsigned e = base + threadIdx.x; e < end; e += TBKT)
        atomicAdd(&cnt[c16[e]], 1u);
    __syncthreads();
    int nbase = b << NPB_SHIFT;
    for (int j = threadIdx.x; j < NPB; j += TBKT) {
        int i = nbase + j;
        if (i < N) deg[i] = cnt[j];
    }
}

// dis[i] = deg>0 ? rsqrt(deg) : 0 (in place over deg); px[i] = dis[i]*x[i]
__global__ void k_dis(unsigned* __restrict__ degdis, const float* __restrict__ x,
                      float* __restrict__ px, int n) {
    int i = blockIdx.x * blockDim.x + threadIdx.x;
    int stride = gridDim.x * blockDim.x;
    float* disf = (float*)degdis;
    for (; i < n; i += stride) {
        unsigned d = degdis[i];
        float v = (d > 0u) ? rsqrtf((float)d) : 0.0f;
        disf[i] = v;
        px[i] = v * x[i];
    }
}

// per-bucket scatter into LDS f32 accumulator + fused z epilogue
__global__ __launch_bounds__(TBKT) void k_scatter_lds(
        const unsigned short* __restrict__ c16, const unsigned* __restrict__ r32,
        const float* __restrict__ px, const unsigned* __restrict__ rowbase,
        const float* __restrict__ x, const float* __restrict__ nw,
        const float* __restrict__ dis, const float* __restrict__ bias,
        float* __restrict__ z, int E, int N, int NB) {
    __shared__ float acc[NPB];
    for (int j = threadIdx.x; j < NPB; j += TBKT) acc[j] = 0.0f;
    __syncthreads();
    int b = blockIdx.x;
    unsigned base = rowbase[b];
    unsigned end = (b == NB - 1) ? (unsigned)E : rowbase[b + 1];
    for (unsigned e = base + threadIdx.x; e < end; e += TBKT)
        atomicAdd(&acc[c16[e]], px[r32[e]]);     // LDS f32 atomic
    __syncthreads();
    int nbase = b << NPB_SHIFT;
    float b0 = bias[0];
    for (int j = threadIdx.x; j < NPB; j += TBKT) {
        int i = nbase + j;
        if (i < N) z[i] = fmaf(x[i], nw[i], fmaf(dis[i], acc[j], b0));
    }
}

__global__ void k_pairs(const float* __restrict__ z, const int* __restrict__ home,
                        const int* __restrict__ away, float* __restrict__ out, int n) {
    int i = blockIdx.x * blockDim.x + threadIdx.x;
    if (i < n) {
        float d = z[home[i]] - z[away[i]];
        out[i] = (d > 0.0f) ? 1.0f : ((d < 0.0f) ? -1.0f : 0.0f);
    }
}

// ---- fallback (round-2 path, device atomics) -------------------------------

__global__ void f_degree(const int* __restrict__ col, int* __restrict__ deg, int e4) {
    int i = blockIdx.x * blockDim.x + threadIdx.x;
    int stride = gridDim.x * blockDim.x;
    const int4* c4 = (const int4*)col;
    for (; i < e4; i += stride) {
        int4 c = c4[i];
        atomicAdd(&deg[c.x], 1); atomicAdd(&deg[c.y], 1);
        atomicAdd(&deg[c.z], 1); atomicAdd(&deg[c.w], 1);
    }
}
__global__ void f_scatter(const int* __restrict__ row, const int* __restrict__ col,
                          const float* __restrict__ px, float* __restrict__ agg, int e4) {
    int i = blockIdx.x * blockDim.x + threadIdx.x;
    int stride = gridDim.x * blockDim.x;
    const int4* r4 = (const int4*)row;
    const int4* c4 = (const int4*)col;
    for (; i < e4; i += stride) {
        int4 r = r4[i];
        int4 c = c4[i];
        atomicAdd(&agg[c.x], px[r.x]); atomicAdd(&agg[c.y], px[r.y]);
        atomicAdd(&agg[c.z], px[r.z]); atomicAdd(&agg[c.w], px[r.w]);
    }
}
__global__ void f_z(const float* __restrict__ x, const float* __restrict__ nw,
                    const float* __restrict__ dis, const float* __restrict__ bias,
                    float* __restrict__ agg, int n) {
    int i = blockIdx.x * blockDim.x + threadIdx.x;
    int stride = gridDim.x * blockDim.x;
    float b = bias[0];
    for (; i < n; i += stride)
        agg[i] = fmaf(x[i], nw[i], fmaf(dis[i], agg[i], b));
}

// ---------------------------------------------------------------------------

extern "C" void kernel_launch(void* const* d_in, const int* in_sizes, int n_in,
                              void* d_out, int out_size, void* d_ws, size_t ws_size,
                              hipStream_t stream) {
    const float* x    = (const float*)d_in[0];
    const float* nw   = (const float*)d_in[1];
    const float* bias = (const float*)d_in[2];
    const int*   ei   = (const int*)d_in[3];
    const int*   home = (const int*)d_in[4];
    const int*   away = (const int*)d_in[5];
    float* out = (float*)d_out;

    const int N = in_sizes[0];          // 500000
    const int E = in_sizes[3] / 2;      // 16000000
    const int P = in_sizes[4];          // 100000

    const int* row = ei;
    const int* col = ei + E;

    const int NB  = (N + NPB - 1) >> NPB_SHIFT;     // 245
    const int cpb = (E + GB - 1) / GB;              // 15625

    auto align256 = [](size_t v) { return (v + 255) & ~(size_t)255; };
    size_t off = 0;
    size_t o_counts = off; off += align256((size_t)NBMAX * GB * 4);  // 1 MB
    size_t o_rowsum = off; off += align256(NBMAX * 4);
    size_t o_rowbas = off; off += align256(NBMAX * 4);
    size_t o_deg    = off; off += align256((size_t)N * 4);           // deg->dis in place
    size_t o_px     = off; off += align256((size_t)N * 4);
    size_t o_z      = off; off += align256((size_t)N * 4);
    size_t o_c16    = off; off += align256((size_t)E * 2);
    size_t o_r32    = off; off += align256((size_t)E * 4);
    size_t need = off;

    if (NB <= NBMAX && ws_size >= need) {
        char* base = (char*)d_ws;
        unsigned*       counts  = (unsigned*)(base + o_counts);
        unsigned*       rowsum  = (unsigned*)(base + o_rowsum);
        unsigned*       rowbase = (unsigned*)(base + o_rowbas);
        unsigned*       deg     = (unsigned*)(base + o_deg);
        float*          px      = (float*)(base + o_px);
        float*          z       = (float*)(base + o_z);
        unsigned short* c16     = (unsigned short*)(base + o_c16);
        unsigned*       r32     = (unsigned*)(base + o_r32);

        k_hist<<<GB, TEDGE, 0, stream>>>(col, counts, E, cpb, NB);
        k_scanA<<<NB, 256, 0, stream>>>(counts, rowsum);
        k_scanB<<<1, 256, 0, stream>>>(rowsum, rowbase, NB);
        k_bin<<<GB, TEDGE, 0, stream>>>(row, col, counts, rowbase, c16, r32, E, cpb, NB);
        k_deg<<<NB, TBKT, 0, stream>>>(c16, rowbase, deg, E, N, NB);
        k_dis<<<2048, 256, 0, stream>>>(deg, x, px, N);
        k_scatter_lds<<<NB, TBKT, 0, stream>>>(c16, r32, px, rowbase, x, nw,
                                               (const float*)deg, bias, z, E, N, NB);
        k_pairs<<<(P + 255) / 256, 256, 0, stream>>>(z, home, away, out, P);
    } else {
        // fallback: device-scope atomics (round-2 behavior)
        size_t slot = align256((size_t)N * 4);
        int*   deg = (int*)d_ws;
        float* agg = (float*)((char*)d_ws + slot);
        float* px  = (float*)((char*)d_ws + 2 * slot);
        const int e4 = E / 4;
        hipMemsetAsync(d_ws, 0, 2 * slot, stream);
        f_degree<<<2048, 256, 0, stream>>>(col, deg, e4);
        k_dis<<<2048, 256, 0, stream>>>((unsigned*)deg, x, px, N);
        f_scatter<<<2048, 256, 0, stream>>>(row, col, px, agg, e4);
        f_z<<<2048, 256, 0, stream>>>(x, nw, (const float*)deg, bias, agg, N);
        k_pairs<<<(P + 255) / 256, 256, 0, stream>>>(agg, home, away, out, P);
    }
}

// Round 5
// 726.447 us; speedup vs baseline: 2.1269x; 1.0392x over previous
//
#include <hip/hip_runtime.h>

// Reference:
//   deg[i] = # edges with col==i ; dis[i] = deg>0 ? rsqrt(deg) : 0
//   agg[c] = dis[c] * sum_{(r,c)} dis[r]*x[r]        (dis[c] factored out)
//   z[i]   = x[i]*nw[i] + agg[i] + bias
//   out[p] = sign(z[home]-z[away])                   (sigmoid monotonic -> dropped)
//
// Round-5: k_bin had 7x write amplification (705MB for 96MB payload; scattered
// 2B/4B stores -> 32B fabric transactions, partial lines evicted by streaming
// reads). Fix: (a) pack (r<<11|c_rel) into ONE u32 (r<2^21, c_rel<2^11);
// (b) LDS staging ring per bucket, flushed in 16-entry groups by lane-parallel
// coalesced stores. Plus: fuse deg+dis, 1024-thread per-bucket kernels.

#define NPB_SHIFT 11
#define NPB       2048          // nodes per bucket
#define NBMAX     256           // max buckets
#define GB        1024          // blocks in edge passes
#define TEDGE     256
#define TBIN      256           // k_bin block size (one round = 256 edges)
#define TBKT      1024          // per-bucket kernels
#define CAP       32            // staging ring entries per bucket (mult of 16)
#define CAPP      33            // padded stride (bank spread)

// ---- block-wide exclusive scan helpers (blockDim == 256) -------------------

__device__ __forceinline__ unsigned wave_incl_scan(unsigned v) {
    #pragma unroll
    for (int d = 1; d < 64; d <<= 1) {
        unsigned n = __shfl_up((int)v, d, 64);
        if ((threadIdx.x & 63) >= (unsigned)d) v += n;
    }
    return v;
}

__device__ __forceinline__ unsigned block_excl_scan256(unsigned v, unsigned* lds,
                                                       unsigned* total) {
    int lane = threadIdx.x & 63, w = threadIdx.x >> 6;
    unsigned incl = wave_incl_scan(v);
    if (lane == 63) lds[w] = incl;
    __syncthreads();
    if (threadIdx.x == 0) {
        unsigned run = 0;
        #pragma unroll
        for (int i = 0; i < 4; ++i) { unsigned t = lds[i]; lds[i] = run; run += t; }
        lds[4] = run;
    }
    __syncthreads();
    unsigned e = incl - v + lds[w];
    *total = lds[4];
    __syncthreads();
    return e;
}

// ---- pipeline kernels ------------------------------------------------------

__global__ __launch_bounds__(TEDGE) void k_hist(const int* __restrict__ col,
                                                unsigned* __restrict__ counts,
                                                int E, int cpb, int NB) {
    __shared__ unsigned hist[NBMAX];
    for (int b = threadIdx.x; b < NBMAX; b += TEDGE) hist[b] = 0;
    __syncthreads();
    int start = blockIdx.x * cpb;
    int end = min(E, start + cpb);
    for (int e = start + threadIdx.x; e < end; e += TEDGE)
        atomicAdd(&hist[((unsigned)col[e]) >> NPB_SHIFT], 1u);
    __syncthreads();
    for (int b = threadIdx.x; b < NB; b += TEDGE)
        counts[(size_t)b * GB + blockIdx.x] = hist[b];
}

__global__ __launch_bounds__(256) void k_scanA(unsigned* __restrict__ counts,
                                               unsigned* __restrict__ rowsum) {
    __shared__ unsigned lds[8];
    unsigned carry = 0;
    #pragma unroll
    for (int ch = 0; ch < GB / 256; ++ch) {
        size_t idx = (size_t)blockIdx.x * GB + ch * 256 + threadIdx.x;
        unsigned v = counts[idx];
        unsigned tot;
        unsigned e = block_excl_scan256(v, lds, &tot);
        counts[idx] = e + carry;
        carry += tot;
    }
    if (threadIdx.x == 0) rowsum[blockIdx.x] = carry;
}

__global__ __launch_bounds__(256) void k_scanB(const unsigned* __restrict__ rowsum,
                                               unsigned* __restrict__ rowbase, int NB) {
    __shared__ unsigned lds[8];
    unsigned v = (threadIdx.x < (unsigned)NB) ? rowsum[threadIdx.x] : 0u;
    unsigned tot;
    unsigned e = block_excl_scan256(v, lds, &tot);
    if (threadIdx.x < (unsigned)NB) rowbase[threadIdx.x] = e;
}

// bucket-sort edges into packed[] = (r << NPB_SHIFT) | c_rel, with LDS staging
// rings flushed as coalesced 16-entry groups.
__global__ __launch_bounds__(TBIN) void k_bin(const int* __restrict__ row,
                                              const int* __restrict__ col,
                                              const unsigned* __restrict__ counts,
                                              const unsigned* __restrict__ rowbase,
                                              unsigned* __restrict__ packed,
                                              int E, int cpb, int NB) {
    __shared__ unsigned stage[NBMAX * CAPP];     // ~33.8 KB
    __shared__ unsigned gbase[NBMAX];
    __shared__ unsigned scnt[NBMAX];
    __shared__ unsigned flushed[NBMAX];

    for (int b = threadIdx.x; b < NB; b += TBIN) {
        gbase[b] = counts[(size_t)b * GB + blockIdx.x] + rowbase[b];
        scnt[b] = 0; flushed[b] = 0;
    }
    __syncthreads();

    int start = blockIdx.x * cpb;
    int end = min(E, start + cpb);
    int wv = threadIdx.x >> 6, lane = threadIdx.x & 63;

    for (int base = start; base < end; base += TBIN) {
        int e = base + threadIdx.x;
        if (e < end) {
            unsigned c = (unsigned)col[e];
            unsigned r = (unsigned)row[e];
            unsigned b = c >> NPB_SHIFT;
            unsigned v = (r << NPB_SHIFT) | (c & (NPB - 1u));
            unsigned pos = atomicAdd(&scnt[b], 1u);
            if (pos - flushed[b] < CAP)                 // flushed stable in round
                stage[b * CAPP + (pos & (CAP - 1))] = v;
            else
                packed[gbase[b] + pos] = v;             // rare overflow: direct
        }
        __syncthreads();
        // flush: wave wv owns buckets b == wv (mod 4); lanes write coalesced
        for (int b = wv; b < NB; b += TBIN / 64) {
            unsigned f = flushed[b], s = scnt[b];
            unsigned pend = s - f;
            unsigned n = (pend >= CAP) ? CAP : (pend & ~15u);
            if (n) {
                unsigned gb = gbase[b];
                if (lane < n)
                    packed[gb + f + lane] = stage[b * CAPP + ((f + lane) & (CAP - 1))];
                if (lane == 0) flushed[b] = (pend >= CAP) ? s : (f + n);
            }
        }
        __syncthreads();
    }
    // tail flush (pend <= 15 per bucket)
    for (int b = wv; b < NB; b += TBIN / 64) {
        unsigned f = flushed[b], s = scnt[b];
        if (f + lane < s)
            packed[gbase[b] + f + lane] = stage[b * CAPP + ((f + lane) & (CAP - 1))];
    }
}

// per-bucket degree (LDS histogram) fused with dis/px computation
__global__ __launch_bounds__(TBKT) void k_degdis(const unsigned* __restrict__ packed,
                                                 const unsigned* __restrict__ rowbase,
                                                 const float* __restrict__ x,
                                                 float* __restrict__ dis,
                                                 float* __restrict__ px,
                                                 int E, int N, int NB) {
    __shared__ unsigned cnt[NPB];
    for (int j = threadIdx.x; j < NPB; j += TBKT) cnt[j] = 0;
    __syncthreads();
    int b = blockIdx.x;
    unsigned base = rowbase[b];
    unsigned end = (b == NB - 1) ? (unsigned)E : rowbase[b + 1];
    #pragma unroll 4
    for (unsigned e = base + threadIdx.x; e < end; e += TBKT)
        atomicAdd(&cnt[packed[e] & (NPB - 1u)], 1u);
    __syncthreads();
    int nbase = b << NPB_SHIFT;
    for (int j = threadIdx.x; j < NPB; j += TBKT) {
        int i = nbase + j;
        if (i < N) {
            unsigned d = cnt[j];
            float v = d ? rsqrtf((float)d) : 0.0f;
            dis[i] = v;
            px[i] = v * x[i];
        }
    }
}

// per-bucket scatter into LDS f32 accumulator + fused z epilogue
__global__ __launch_bounds__(TBKT) void k_scatter_z(
        const unsigned* __restrict__ packed, const float* __restrict__ px,
        const unsigned* __restrict__ rowbase, const float* __restrict__ x,
        const float* __restrict__ nw, const float* __restrict__ dis,
        const float* __restrict__ bias, float* __restrict__ z,
        int E, int N, int NB) {
    __shared__ float acc[NPB];
    for (int j = threadIdx.x; j < NPB; j += TBKT) acc[j] = 0.0f;
    __syncthreads();
    int b = blockIdx.x;
    unsigned base = rowbase[b];
    unsigned end = (b == NB - 1) ? (unsigned)E : rowbase[b + 1];
    #pragma unroll 4
    for (unsigned e = base + threadIdx.x; e < end; e += TBKT) {
        unsigned v = packed[e];
        atomicAdd(&acc[v & (NPB - 1u)], px[v >> NPB_SHIFT]);   // LDS f32 atomic
    }
    __syncthreads();
    int nbase = b << NPB_SHIFT;
    float b0 = bias[0];
    for (int j = threadIdx.x; j < NPB; j += TBKT) {
        int i = nbase + j;
        if (i < N) z[i] = fmaf(x[i], nw[i], fmaf(dis[i], acc[j], b0));
    }
}

__global__ void k_pairs(const float* __restrict__ z, const int* __restrict__ home,
                        const int* __restrict__ away, float* __restrict__ out, int n) {
    int i = blockIdx.x * blockDim.x + threadIdx.x;
    if (i < n) {
        float d = z[home[i]] - z[away[i]];
        out[i] = (d > 0.0f) ? 1.0f : ((d < 0.0f) ? -1.0f : 0.0f);
    }
}

// ---- fallback (device atomics) --------------------------------------------

__global__ void f_degree(const int* __restrict__ col, int* __restrict__ deg, int e4) {
    int i = blockIdx.x * blockDim.x + threadIdx.x;
    int stride = gridDim.x * blockDim.x;
    const int4* c4 = (const int4*)col;
    for (; i < e4; i += stride) {
        int4 c = c4[i];
        atomicAdd(&deg[c.x], 1); atomicAdd(&deg[c.y], 1);
        atomicAdd(&deg[c.z], 1); atomicAdd(&deg[c.w], 1);
    }
}
__global__ void f_dis(unsigned* __restrict__ degdis, const float* __restrict__ x,
                      float* __restrict__ px, int n) {
    int i = blockIdx.x * blockDim.x + threadIdx.x;
    int stride = gridDim.x * blockDim.x;
    float* disf = (float*)degdis;
    for (; i < n; i += stride) {
        unsigned d = degdis[i];
        float v = (d > 0u) ? rsqrtf((float)d) : 0.0f;
        disf[i] = v;
        px[i] = v * x[i];
    }
}
__global__ void f_scatter(const int* __restrict__ row, const int* __restrict__ col,
                          const float* __restrict__ px, float* __restrict__ agg, int e4) {
    int i = blockIdx.x * blockDim.x + threadIdx.x;
    int stride = gridDim.x * blockDim.x;
    const int4* r4 = (const int4*)row;
    const int4* c4 = (const int4*)col;
    for (; i < e4; i += stride) {
        int4 r = r4[i];
        int4 c = c4[i];
        atomicAdd(&agg[c.x], px[r.x]); atomicAdd(&agg[c.y], px[r.y]);
        atomicAdd(&agg[c.z], px[r.z]); atomicAdd(&agg[c.w], px[r.w]);
    }
}
__global__ void f_z(const float* __restrict__ x, const float* __restrict__ nw,
                    const float* __restrict__ dis, const float* __restrict__ bias,
                    float* __restrict__ agg, int n) {
    int i = blockIdx.x * blockDim.x + threadIdx.x;
    int stride = gridDim.x * blockDim.x;
    float b = bias[0];
    for (; i < n; i += stride)
        agg[i] = fmaf(x[i], nw[i], fmaf(dis[i], agg[i], b));
}

// ---------------------------------------------------------------------------

extern "C" void kernel_launch(void* const* d_in, const int* in_sizes, int n_in,
                              void* d_out, int out_size, void* d_ws, size_t ws_size,
                              hipStream_t stream) {
    const float* x    = (const float*)d_in[0];
    const float* nw   = (const float*)d_in[1];
    const float* bias = (const float*)d_in[2];
    const int*   ei   = (const int*)d_in[3];
    const int*   home = (const int*)d_in[4];
    const int*   away = (const int*)d_in[5];
    float* out = (float*)d_out;

    const int N = in_sizes[0];          // 500000
    const int E = in_sizes[3] / 2;      // 16000000
    const int P = in_sizes[4];          // 100000

    const int* row = ei;
    const int* col = ei + E;

    const int NB  = (N + NPB - 1) >> NPB_SHIFT;     // 245
    const int cpb = (E + GB - 1) / GB;              // 15625

    auto align256 = [](size_t v) { return (v + 255) & ~(size_t)255; };
    size_t off = 0;
    size_t o_counts = off; off += align256((size_t)NBMAX * GB * 4);  // 1 MB
    size_t o_rowsum = off; off += align256(NBMAX * 4);
    size_t o_rowbas = off; off += align256(NBMAX * 4);
    size_t o_dis    = off; off += align256((size_t)N * 4);
    size_t o_px     = off; off += align256((size_t)N * 4);
    size_t o_z      = off; off += align256((size_t)N * 4);
    size_t o_pack   = off; off += align256((size_t)E * 4);           // 64 MB
    size_t need = off;

    bool fast = (NB <= NBMAX) && ((size_t)N <= (1u << (32 - NPB_SHIFT)))
                && (ws_size >= need);

    if (fast) {
        char* base = (char*)d_ws;
        unsigned* counts  = (unsigned*)(base + o_counts);
        unsigned* rowsum  = (unsigned*)(base + o_rowsum);
        unsigned* rowbase = (unsigned*)(base + o_rowbas);
        float*    dis     = (float*)(base + o_dis);
        float*    px      = (float*)(base + o_px);
        float*    z       = (float*)(base + o_z);
        unsigned* packed  = (unsigned*)(base + o_pack);

        k_hist<<<GB, TEDGE, 0, stream>>>(col, counts, E, cpb, NB);
        k_scanA<<<NB, 256, 0, stream>>>(counts, rowsum);
        k_scanB<<<1, 256, 0, stream>>>(rowsum, rowbase, NB);
        k_bin<<<GB, TBIN, 0, stream>>>(row, col, counts, rowbase, packed, E, cpb, NB);
        k_degdis<<<NB, TBKT, 0, stream>>>(packed, rowbase, x, dis, px, E, N, NB);
        k_scatter_z<<<NB, TBKT, 0, stream>>>(packed, px, rowbase, x, nw, dis, bias,
                                             z, E, N, NB);
        k_pairs<<<(P + 255) / 256, 256, 0, stream>>>(z, home, away, out, P);
    } else {
        size_t slot = align256((size_t)N * 4);
        int*   deg = (int*)d_ws;
        float* agg = (float*)((char*)d_ws + slot);
        float* px  = (float*)((char*)d_ws + 2 * slot);
        const int e4 = E / 4;
        hipMemsetAsync(d_ws, 0, 2 * slot, stream);
        f_degree<<<2048, 256, 0, stream>>>(col, deg, e4);
        f_dis<<<2048, 256, 0, stream>>>((unsigned*)deg, x, px, N);
        f_scatter<<<2048, 256, 0, stream>>>(row, col, px, agg, e4);
        f_z<<<2048, 256, 0, stream>>>(x, nw, (const float*)deg, bias, agg, N);
        k_pairs<<<(P + 255) / 256, 256, 0, stream>>>(agg, home, away, out, P);
    }
}

// Round 6
// 390.036 us; speedup vs baseline: 3.9613x; 1.8625x over previous
//
#include <hip/hip_runtime.h>

// Reference:
//   deg[i] = # edges with col==i ; dis[i] = deg>0 ? rsqrt(deg) : 0
//   agg[c] = dis[c] * sum_{(r,c)} dis[r]*x[r]        (dis[c] factored out)
//   z[i]   = x[i]*nw[i] + agg[i] + bias
//   out[p] = sign(z[home]-z[away])                   (sigmoid monotonic -> dropped)
//
// Round-6: k_bin was issue-bound (VALUBusy 55%) on the flush-scan machinery
// (61 rounds x ~61 scan iters/wave with TBIN=256). Fix: TBIN=1024 + int2
// edge loads -> 2048 edges/round, 8 rounds, ~120 scan iters/wave total,
// 16 barriers instead of 122. Memory behavior already good (WRITE=95MB).

#define NPB_SHIFT 11
#define NPB       2048          // nodes per bucket
#define NBMAX     256           // max buckets
#define GB        1024          // blocks in edge passes
#define TEDGE     256           // k_hist block size
#define TBIN      1024          // k_bin block size
#define VEC       2             // edges per thread per round in k_bin
#define TBKT      1024          // per-bucket kernels
#define CAP       32            // staging ring entries per bucket (pow2)
#define CAPP      33            // padded stride (bank spread)

// ---- block-wide exclusive scan helpers (blockDim == 256) -------------------

__device__ __forceinline__ unsigned wave_incl_scan(unsigned v) {
    #pragma unroll
    for (int d = 1; d < 64; d <<= 1) {
        unsigned n = __shfl_up((int)v, d, 64);
        if ((threadIdx.x & 63) >= (unsigned)d) v += n;
    }
    return v;
}

__device__ __forceinline__ unsigned block_excl_scan256(unsigned v, unsigned* lds,
                                                       unsigned* total) {
    int lane = threadIdx.x & 63, w = threadIdx.x >> 6;
    unsigned incl = wave_incl_scan(v);
    if (lane == 63) lds[w] = incl;
    __syncthreads();
    if (threadIdx.x == 0) {
        unsigned run = 0;
        #pragma unroll
        for (int i = 0; i < 4; ++i) { unsigned t = lds[i]; lds[i] = run; run += t; }
        lds[4] = run;
    }
    __syncthreads();
    unsigned e = incl - v + lds[w];
    *total = lds[4];
    __syncthreads();
    return e;
}

// ---- pipeline kernels ------------------------------------------------------

__global__ __launch_bounds__(TEDGE) void k_hist(const int* __restrict__ col,
                                                unsigned* __restrict__ counts,
                                                int E, int cpb, int NB) {
    __shared__ unsigned hist[NBMAX];
    for (int b = threadIdx.x; b < NBMAX; b += TEDGE) hist[b] = 0;
    __syncthreads();
    int start = blockIdx.x * cpb;
    int end = min(E, start + cpb);
    int e = start + threadIdx.x * 4;
    for (; e + 3 < end; e += TEDGE * 4) {
        int4 c = *(const int4*)(col + e);
        atomicAdd(&hist[(unsigned)c.x >> NPB_SHIFT], 1u);
        atomicAdd(&hist[(unsigned)c.y >> NPB_SHIFT], 1u);
        atomicAdd(&hist[(unsigned)c.z >> NPB_SHIFT], 1u);
        atomicAdd(&hist[(unsigned)c.w >> NPB_SHIFT], 1u);
    }
    #pragma unroll
    for (int k = 0; k < 4; ++k)
        if (e + k < end) atomicAdd(&hist[(unsigned)col[e + k] >> NPB_SHIFT], 1u);
    __syncthreads();
    for (int b = threadIdx.x; b < NB; b += TEDGE)
        counts[(size_t)b * GB + blockIdx.x] = hist[b];
}

__global__ __launch_bounds__(256) void k_scanA(unsigned* __restrict__ counts,
                                               unsigned* __restrict__ rowsum) {
    __shared__ unsigned lds[8];
    unsigned carry = 0;
    #pragma unroll
    for (int ch = 0; ch < GB / 256; ++ch) {
        size_t idx = (size_t)blockIdx.x * GB + ch * 256 + threadIdx.x;
        unsigned v = counts[idx];
        unsigned tot;
        unsigned e = block_excl_scan256(v, lds, &tot);
        counts[idx] = e + carry;
        carry += tot;
    }
    if (threadIdx.x == 0) rowsum[blockIdx.x] = carry;
}

__global__ __launch_bounds__(256) void k_scanB(const unsigned* __restrict__ rowsum,
                                               unsigned* __restrict__ rowbase, int NB) {
    __shared__ unsigned lds[8];
    unsigned v = (threadIdx.x < (unsigned)NB) ? rowsum[threadIdx.x] : 0u;
    unsigned tot;
    unsigned e = block_excl_scan256(v, lds, &tot);
    if (threadIdx.x < (unsigned)NB) rowbase[threadIdx.x] = e;
}

// bucket-sort edges into packed[] = (r << NPB_SHIFT) | c_rel, LDS staging rings
// flushed as coalesced 16..32-entry groups.
__global__ __launch_bounds__(TBIN) void k_bin(const int* __restrict__ row,
                                              const int* __restrict__ col,
                                              const unsigned* __restrict__ counts,
                                              const unsigned* __restrict__ rowbase,
                                              unsigned* __restrict__ packed,
                                              int E, int cpb, int NB) {
    __shared__ unsigned stage[NBMAX * CAPP];     // 33.8 KB
    __shared__ unsigned gbase[NBMAX];
    __shared__ unsigned scnt[NBMAX];
    __shared__ unsigned flushed[NBMAX];

    for (int b = threadIdx.x; b < NB; b += TBIN) {
        gbase[b] = counts[(size_t)b * GB + blockIdx.x] + rowbase[b];
        scnt[b] = 0; flushed[b] = 0;
    }
    __syncthreads();

    int start = blockIdx.x * cpb;
    int end = min(E, start + cpb);
    int wv = threadIdx.x >> 6, lane = threadIdx.x & 63;
    const int RB = TBIN * VEC;                   // edges per round

#define PROC(cc, rr) {                                                        \
        unsigned b_ = (unsigned)(cc) >> NPB_SHIFT;                            \
        unsigned v_ = ((unsigned)(rr) << NPB_SHIFT) | ((unsigned)(cc) & (NPB - 1u)); \
        unsigned pos_ = atomicAdd(&scnt[b_], 1u);                             \
        if (pos_ - flushed[b_] < CAP)                                         \
            stage[b_ * CAPP + (pos_ & (CAP - 1u))] = v_;                      \
        else                                                                  \
            packed[gbase[b_] + pos_] = v_; }

    for (int base = start; base < end; base += RB) {
        int e = base + threadIdx.x * VEC;
        if (e + VEC - 1 < end) {
            int2 c2 = *(const int2*)(col + e);
            int2 r2 = *(const int2*)(row + e);
            PROC(c2.x, r2.x);
            PROC(c2.y, r2.y);
        } else {
            #pragma unroll
            for (int k = 0; k < VEC; ++k)
                if (e + k < end) { PROC(col[e + k], row[e + k]); }
        }
        __syncthreads();
        // flush: wave wv owns buckets b == wv (mod 16)
        for (int b = wv; b < NB; b += TBIN / 64) {
            unsigned f = flushed[b], s = scnt[b];
            unsigned pend = s - f;
            unsigned n = (pend >= CAP) ? CAP : (pend & ~15u);
            if (n) {
                unsigned gb = gbase[b];
                if (lane < n)
                    packed[gb + f + lane] = stage[b * CAPP + ((f + lane) & (CAP - 1))];
                if (lane == 0) flushed[b] = (pend >= CAP) ? s : (f + n);
            }
        }
        __syncthreads();
    }
    // tail flush (pend <= 15 per bucket)
    for (int b = wv; b < NB; b += TBIN / 64) {
        unsigned f = flushed[b], s = scnt[b];
        if (f + lane < s)
            packed[gbase[b] + f + lane] = stage[b * CAPP + ((f + lane) & (CAP - 1))];
    }
#undef PROC
}

// per-bucket degree (LDS histogram) fused with dis/px computation
__global__ __launch_bounds__(TBKT) void k_degdis(const unsigned* __restrict__ packed,
                                                 const unsigned* __restrict__ rowbase,
                                                 const float* __restrict__ x,
                                                 float* __restrict__ dis,
                                                 float* __restrict__ px,
                                                 int E, int N, int NB) {
    __shared__ unsigned cnt[NPB];
    for (int j = threadIdx.x; j < NPB; j += TBKT) cnt[j] = 0;
    __syncthreads();
    int b = blockIdx.x;
    unsigned base = rowbase[b];
    unsigned end = (b == NB - 1) ? (unsigned)E : rowbase[b + 1];
    #pragma unroll 4
    for (unsigned e = base + threadIdx.x; e < end; e += TBKT)
        atomicAdd(&cnt[packed[e] & (NPB - 1u)], 1u);
    __syncthreads();
    int nbase = b << NPB_SHIFT;
    for (int j = threadIdx.x; j < NPB; j += TBKT) {
        int i = nbase + j;
        if (i < N) {
            unsigned d = cnt[j];
            float v = d ? rsqrtf((float)d) : 0.0f;
            dis[i] = v;
            px[i] = v * x[i];
        }
    }
}

// per-bucket scatter into LDS f32 accumulator + fused z epilogue
__global__ __launch_bounds__(TBKT) void k_scatter_z(
        const unsigned* __restrict__ packed, const float* __restrict__ px,
        const unsigned* __restrict__ rowbase, const float* __restrict__ x,
        const float* __restrict__ nw, const float* __restrict__ dis,
        const float* __restrict__ bias, float* __restrict__ z,
        int E, int N, int NB) {
    __shared__ float acc[NPB];
    for (int j = threadIdx.x; j < NPB; j += TBKT) acc[j] = 0.0f;
    __syncthreads();
    int b = blockIdx.x;
    unsigned base = rowbase[b];
    unsigned end = (b == NB - 1) ? (unsigned)E : rowbase[b + 1];
    #pragma unroll 4
    for (unsigned e = base + threadIdx.x; e < end; e += TBKT) {
        unsigned v = packed[e];
        atomicAdd(&acc[v & (NPB - 1u)], px[v >> NPB_SHIFT]);   // LDS f32 atomic
    }
    __syncthreads();
    int nbase = b << NPB_SHIFT;
    float b0 = bias[0];
    for (int j = threadIdx.x; j < NPB; j += TBKT) {
        int i = nbase + j;
        if (i < N) z[i] = fmaf(x[i], nw[i], fmaf(dis[i], acc[j], b0));
    }
}

__global__ void k_pairs(const float* __restrict__ z, const int* __restrict__ home,
                        const int* __restrict__ away, float* __restrict__ out, int n) {
    int i = blockIdx.x * blockDim.x + threadIdx.x;
    if (i < n) {
        float d = z[home[i]] - z[away[i]];
        out[i] = (d > 0.0f) ? 1.0f : ((d < 0.0f) ? -1.0f : 0.0f);
    }
}

// ---- fallback (device atomics) --------------------------------------------

__global__ void f_degree(const int* __restrict__ col, int* __restrict__ deg, int e4) {
    int i = blockIdx.x * blockDim.x + threadIdx.x;
    int stride = gridDim.x * blockDim.x;
    const int4* c4 = (const int4*)col;
    for (; i < e4; i += stride) {
        int4 c = c4[i];
        atomicAdd(&deg[c.x], 1); atomicAdd(&deg[c.y], 1);
        atomicAdd(&deg[c.z], 1); atomicAdd(&deg[c.w], 1);
    }
}
__global__ void f_dis(unsigned* __restrict__ degdis, const float* __restrict__ x,
                      float* __restrict__ px, int n) {
    int i = blockIdx.x * blockDim.x + threadIdx.x;
    int stride = gridDim.x * blockDim.x;
    float* disf = (float*)degdis;
    for (; i < n; i += stride) {
        unsigned d = degdis[i];
        float v = (d > 0u) ? rsqrtf((float)d) : 0.0f;
        disf[i] = v;
        px[i] = v * x[i];
    }
}
__global__ void f_scatter(const int* __restrict__ row, const int* __restrict__ col,
                          const float* __restrict__ px, float* __restrict__ agg, int e4) {
    int i = blockIdx.x * blockDim.x + threadIdx.x;
    int stride = gridDim.x * blockDim.x;
    const int4* r4 = (const int4*)row;
    const int4* c4 = (const int4*)col;
    for (; i < e4; i += stride) {
        int4 r = r4[i];
        int4 c = c4[i];
        atomicAdd(&agg[c.x], px[r.x]); atomicAdd(&agg[c.y], px[r.y]);
        atomicAdd(&agg[c.z], px[r.z]); atomicAdd(&agg[c.w], px[r.w]);
    }
}
__global__ void f_z(const float* __restrict__ x, const float* __restrict__ nw,
                    const float* __restrict__ dis, const float* __restrict__ bias,
                    float* __restrict__ agg, int n) {
    int i = blockIdx.x * blockDim.x + threadIdx.x;
    int stride = gridDim.x * blockDim.x;
    float b = bias[0];
    for (; i < n; i += stride)
        agg[i] = fmaf(x[i], nw[i], fmaf(dis[i], agg[i], b));
}

// ---------------------------------------------------------------------------

extern "C" void kernel_launch(void* const* d_in, const int* in_sizes, int n_in,
                              void* d_out, int out_size, void* d_ws, size_t ws_size,
                              hipStream_t stream) {
    const float* x    = (const float*)d_in[0];
    const float* nw   = (const float*)d_in[1];
    const float* bias = (const float*)d_in[2];
    const int*   ei   = (const int*)d_in[3];
    const int*   home = (const int*)d_in[4];
    const int*   away = (const int*)d_in[5];
    float* out = (float*)d_out;

    const int N = in_sizes[0];          // 500000
    const int E = in_sizes[3] / 2;      // 16000000
    const int P = in_sizes[4];          // 100000

    const int* row = ei;
    const int* col = ei + E;

    const int NB  = (N + NPB - 1) >> NPB_SHIFT;           // 245
    const int cpb = (((E + GB - 1) / GB) + 3) & ~3;       // 15628 (mult of 4)

    auto align256 = [](size_t v) { return (v + 255) & ~(size_t)255; };
    size_t off = 0;
    size_t o_counts = off; off += align256((size_t)NBMAX * GB * 4);  // 1 MB
    size_t o_rowsum = off; off += align256(NBMAX * 4);
    size_t o_rowbas = off; off += align256(NBMAX * 4);
    size_t o_dis    = off; off += align256((size_t)N * 4);
    size_t o_px     = off; off += align256((size_t)N * 4);
    size_t o_z      = off; off += align256((size_t)N * 4);
    size_t o_pack   = off; off += align256((size_t)E * 4);           // 64 MB
    size_t need = off;

    bool fast = (NB <= NBMAX) && ((size_t)N <= (1u << (32 - NPB_SHIFT)))
                && (ws_size >= need);

    if (fast) {
        char* base = (char*)d_ws;
        unsigned* counts  = (unsigned*)(base + o_counts);
        unsigned* rowsum  = (unsigned*)(base + o_rowsum);
        unsigned* rowbase = (unsigned*)(base + o_rowbas);
        float*    dis     = (float*)(base + o_dis);
        float*    px      = (float*)(base + o_px);
        float*    z       = (float*)(base + o_z);
        unsigned* packed  = (unsigned*)(base + o_pack);

        k_hist<<<GB, TEDGE, 0, stream>>>(col, counts, E, cpb, NB);
        k_scanA<<<NB, 256, 0, stream>>>(counts, rowsum);
        k_scanB<<<1, 256, 0, stream>>>(rowsum, rowbase, NB);
        k_bin<<<GB, TBIN, 0, stream>>>(row, col, counts, rowbase, packed, E, cpb, NB);
        k_degdis<<<NB, TBKT, 0, stream>>>(packed, rowbase, x, dis, px, E, N, NB);
        k_scatter_z<<<NB, TBKT, 0, stream>>>(packed, px, rowbase, x, nw, dis, bias,
                                             z, E, N, NB);
        k_pairs<<<(P + 255) / 256, 256, 0, stream>>>(z, home, away, out, P);
    } else {
        size_t slot = align256((size_t)N * 4);
        int*   deg = (int*)d_ws;
        float* agg = (float*)((char*)d_ws + slot);
        float* px  = (float*)((char*)d_ws + 2 * slot);
        const int e4 = E / 4;
        hipMemsetAsync(d_ws, 0, 2 * slot, stream);
        f_degree<<<2048, 256, 0, stream>>>(col, deg, e4);
        f_dis<<<2048, 256, 0, stream>>>((unsigned*)deg, x, px, N);
        f_scatter<<<2048, 256, 0, stream>>>(row, col, px, agg, e4);
        f_z<<<2048, 256, 0, stream>>>(x, nw, (const float*)deg, bias, agg, N);
        k_pairs<<<(P + 255) / 256, 256, 0, stream>>>(agg, home, away, out, P);
    }
}

// Round 7
// 386.322 us; speedup vs baseline: 3.9994x; 1.0096x over previous
//
#include <hip/hip_runtime.h>

// Reference:
//   deg[i] = # edges with col==i ; dis[i] = deg>0 ? rsqrt(deg) : 0
//   agg[c] = dis[c] * sum_{(r,c)} dis[r]*x[r]        (dis[c] factored out)
//   z[i]   = x[i]*nw[i] + agg[i] + bias
//   out[p] = sign(z[home]-z[away])                   (sigmoid monotonic -> dropped)
//
// Round-7: k_scatter_z/k_degdis were latency-bound at 245 blocks (1 block/CU,
// VALUBusy 3%, occupancy 41%). Split each bucket into S=8 slices processed by
// independent 512-thread blocks (grid 1960, full occupancy), each writing a
// coalesced per-slice partial (LDS hist/acc); small merge kernels (245 blocks)
// reduce the S partials and fuse dis/px resp. the z epilogue.

#define NPB_SHIFT 11
#define NPB       2048          // nodes per bucket
#define NBMAX     256           // max buckets
#define GB        1024          // blocks in edge passes
#define TEDGE     256           // k_hist block size
#define TBIN      1024          // k_bin block size
#define VEC       2             // edges/thread/round in k_bin
#define TSL       512           // slice kernels block size
#define SSPLIT    8             // slices per bucket
#define TMERGE    1024          // merge kernels block size
#define CAP       32            // staging ring entries per bucket (pow2)
#define CAPP      33            // padded stride (bank spread)

// ---- block-wide exclusive scan helpers (blockDim == 256) -------------------

__device__ __forceinline__ unsigned wave_incl_scan(unsigned v) {
    #pragma unroll
    for (int d = 1; d < 64; d <<= 1) {
        unsigned n = __shfl_up((int)v, d, 64);
        if ((threadIdx.x & 63) >= (unsigned)d) v += n;
    }
    return v;
}

__device__ __forceinline__ unsigned block_excl_scan256(unsigned v, unsigned* lds,
                                                       unsigned* total) {
    int lane = threadIdx.x & 63, w = threadIdx.x >> 6;
    unsigned incl = wave_incl_scan(v);
    if (lane == 63) lds[w] = incl;
    __syncthreads();
    if (threadIdx.x == 0) {
        unsigned run = 0;
        #pragma unroll
        for (int i = 0; i < 4; ++i) { unsigned t = lds[i]; lds[i] = run; run += t; }
        lds[4] = run;
    }
    __syncthreads();
    unsigned e = incl - v + lds[w];
    *total = lds[4];
    __syncthreads();
    return e;
}

// ---- pipeline kernels ------------------------------------------------------

__global__ __launch_bounds__(TEDGE) void k_hist(const int* __restrict__ col,
                                                unsigned* __restrict__ counts,
                                                int E, int cpb, int NB) {
    __shared__ unsigned hist[NBMAX];
    for (int b = threadIdx.x; b < NBMAX; b += TEDGE) hist[b] = 0;
    __syncthreads();
    int start = blockIdx.x * cpb;
    int end = min(E, start + cpb);
    int e = start + threadIdx.x * 4;
    for (; e + 3 < end; e += TEDGE * 4) {
        int4 c = *(const int4*)(col + e);
        atomicAdd(&hist[(unsigned)c.x >> NPB_SHIFT], 1u);
        atomicAdd(&hist[(unsigned)c.y >> NPB_SHIFT], 1u);
        atomicAdd(&hist[(unsigned)c.z >> NPB_SHIFT], 1u);
        atomicAdd(&hist[(unsigned)c.w >> NPB_SHIFT], 1u);
    }
    #pragma unroll
    for (int k = 0; k < 4; ++k)
        if (e + k < end) atomicAdd(&hist[(unsigned)col[e + k] >> NPB_SHIFT], 1u);
    __syncthreads();
    for (int b = threadIdx.x; b < NB; b += TEDGE)
        counts[(size_t)b * GB + blockIdx.x] = hist[b];
}

__global__ __launch_bounds__(256) void k_scanA(unsigned* __restrict__ counts,
                                               unsigned* __restrict__ rowsum) {
    __shared__ unsigned lds[8];
    unsigned carry = 0;
    #pragma unroll
    for (int ch = 0; ch < GB / 256; ++ch) {
        size_t idx = (size_t)blockIdx.x * GB + ch * 256 + threadIdx.x;
        unsigned v = counts[idx];
        unsigned tot;
        unsigned e = block_excl_scan256(v, lds, &tot);
        counts[idx] = e + carry;
        carry += tot;
    }
    if (threadIdx.x == 0) rowsum[blockIdx.x] = carry;
}

__global__ __launch_bounds__(256) void k_scanB(const unsigned* __restrict__ rowsum,
                                               unsigned* __restrict__ rowbase, int NB) {
    __shared__ unsigned lds[8];
    unsigned v = (threadIdx.x < (unsigned)NB) ? rowsum[threadIdx.x] : 0u;
    unsigned tot;
    unsigned e = block_excl_scan256(v, lds, &tot);
    if (threadIdx.x < (unsigned)NB) rowbase[threadIdx.x] = e;
}

// bucket-sort edges into packed[] = (r << NPB_SHIFT) | c_rel, LDS staging rings
// flushed as coalesced 16..32-entry groups.
__global__ __launch_bounds__(TBIN) void k_bin(const int* __restrict__ row,
                                              const int* __restrict__ col,
                                              const unsigned* __restrict__ counts,
                                              const unsigned* __restrict__ rowbase,
                                              unsigned* __restrict__ packed,
                                              int E, int cpb, int NB) {
    __shared__ unsigned stage[NBMAX * CAPP];     // 33.8 KB
    __shared__ unsigned gbase[NBMAX];
    __shared__ unsigned scnt[NBMAX];
    __shared__ unsigned flushed[NBMAX];

    for (int b = threadIdx.x; b < NB; b += TBIN) {
        gbase[b] = counts[(size_t)b * GB + blockIdx.x] + rowbase[b];
        scnt[b] = 0; flushed[b] = 0;
    }
    __syncthreads();

    int start = blockIdx.x * cpb;
    int end = min(E, start + cpb);
    int wv = threadIdx.x >> 6, lane = threadIdx.x & 63;
    const int RB = TBIN * VEC;

#define PROC(cc, rr) {                                                        \
        unsigned b_ = (unsigned)(cc) >> NPB_SHIFT;                            \
        unsigned v_ = ((unsigned)(rr) << NPB_SHIFT) | ((unsigned)(cc) & (NPB - 1u)); \
        unsigned pos_ = atomicAdd(&scnt[b_], 1u);                             \
        if (pos_ - flushed[b_] < CAP)                                         \
            stage[b_ * CAPP + (pos_ & (CAP - 1u))] = v_;                      \
        else                                                                  \
            packed[gbase[b_] + pos_] = v_; }

    for (int base = start; base < end; base += RB) {
        int e = base + threadIdx.x * VEC;
        if (e + VEC - 1 < end) {
            int2 c2 = *(const int2*)(col + e);
            int2 r2 = *(const int2*)(row + e);
            PROC(c2.x, r2.x);
            PROC(c2.y, r2.y);
        } else {
            #pragma unroll
            for (int k = 0; k < VEC; ++k)
                if (e + k < end) { PROC(col[e + k], row[e + k]); }
        }
        __syncthreads();
        for (int b = wv; b < NB; b += TBIN / 64) {
            unsigned f = flushed[b], s = scnt[b];
            unsigned pend = s - f;
            unsigned n = (pend >= CAP) ? CAP : (pend & ~15u);
            if (n) {
                unsigned gb = gbase[b];
                if (lane < n)
                    packed[gb + f + lane] = stage[b * CAPP + ((f + lane) & (CAP - 1))];
                if (lane == 0) flushed[b] = (pend >= CAP) ? s : (f + n);
            }
        }
        __syncthreads();
    }
    for (int b = wv; b < NB; b += TBIN / 64) {
        unsigned f = flushed[b], s = scnt[b];
        if (f + lane < s)
            packed[gbase[b] + f + lane] = stage[b * CAPP + ((f + lane) & (CAP - 1))];
    }
#undef PROC
}

// slice-degree: block (b,s) histograms slice s of bucket b into LDS, writes
// partial counts coalesced to pcnt[(b*S+s)*NPB + j].
__global__ __launch_bounds__(TSL) void k_deg_slice(const unsigned* __restrict__ packed,
                                                   const unsigned* __restrict__ rowbase,
                                                   unsigned* __restrict__ pcnt,
                                                   int E, int NB) {
    __shared__ unsigned cnt[NPB];
    for (int j = threadIdx.x; j < NPB; j += TSL) cnt[j] = 0;
    __syncthreads();
    int b = blockIdx.x / SSPLIT, s = blockIdx.x % SSPLIT;
    unsigned base = rowbase[b];
    unsigned end = (b == NB - 1) ? (unsigned)E : rowbase[b + 1];
    unsigned len = end - base;
    unsigned sl = (len + SSPLIT - 1) / SSPLIT;
    unsigned sb = base + s * sl;
    unsigned se = min(end, sb + sl);
    #pragma unroll 4
    for (unsigned e = sb + threadIdx.x; e < se; e += TSL)
        atomicAdd(&cnt[packed[e] & (NPB - 1u)], 1u);
    __syncthreads();
    unsigned* dst = pcnt + (size_t)blockIdx.x * NPB;
    for (int j = threadIdx.x; j < NPB; j += TSL) dst[j] = cnt[j];
}

// merge S count-partials -> deg -> dis, px
__global__ __launch_bounds__(TMERGE) void k_dis(const unsigned* __restrict__ pcnt,
                                                const float* __restrict__ x,
                                                float* __restrict__ dis,
                                                float* __restrict__ px,
                                                int N, int NB) {
    int b = blockIdx.x;
    const unsigned* src = pcnt + (size_t)b * SSPLIT * NPB;
    int nbase = b << NPB_SHIFT;
    for (int j = threadIdx.x; j < NPB; j += TMERGE) {
        int i = nbase + j;
        if (i < N) {
            unsigned d = 0;
            #pragma unroll
            for (int s = 0; s < SSPLIT; ++s) d += src[s * NPB + j];
            float v = d ? rsqrtf((float)d) : 0.0f;
            dis[i] = v;
            px[i] = v * x[i];
        }
    }
}

// slice-scatter: block (b,s) accumulates slice s of bucket b into LDS f32,
// writes partial sums coalesced to pacc[(b*S+s)*NPB + j].
__global__ __launch_bounds__(TSL) void k_scatter_slice(
        const unsigned* __restrict__ packed, const float* __restrict__ px,
        const unsigned* __restrict__ rowbase, float* __restrict__ pacc,
        int E, int NB) {
    __shared__ float acc[NPB];
    for (int j = threadIdx.x; j < NPB; j += TSL) acc[j] = 0.0f;
    __syncthreads();
    int b = blockIdx.x / SSPLIT, s = blockIdx.x % SSPLIT;
    unsigned base = rowbase[b];
    unsigned end = (b == NB - 1) ? (unsigned)E : rowbase[b + 1];
    unsigned len = end - base;
    unsigned sl = (len + SSPLIT - 1) / SSPLIT;
    unsigned sb = base + s * sl;
    unsigned se = min(end, sb + sl);
    #pragma unroll 4
    for (unsigned e = sb + threadIdx.x; e < se; e += TSL) {
        unsigned v = packed[e];
        atomicAdd(&acc[v & (NPB - 1u)], px[v >> NPB_SHIFT]);
    }
    __syncthreads();
    float* dst = pacc + (size_t)blockIdx.x * NPB;
    for (int j = threadIdx.x; j < NPB; j += TSL) dst[j] = acc[j];
}

// merge S sum-partials -> agg -> z epilogue
__global__ __launch_bounds__(TMERGE) void k_z(const float* __restrict__ pacc,
                                              const float* __restrict__ x,
                                              const float* __restrict__ nw,
                                              const float* __restrict__ dis,
                                              const float* __restrict__ bias,
                                              float* __restrict__ z, int N, int NB) {
    int b = blockIdx.x;
    const float* src = pacc + (size_t)b * SSPLIT * NPB;
    int nbase = b << NPB_SHIFT;
    float b0 = bias[0];
    for (int j = threadIdx.x; j < NPB; j += TMERGE) {
        int i = nbase + j;
        if (i < N) {
            float a = 0.0f;
            #pragma unroll
            for (int s = 0; s < SSPLIT; ++s) a += src[s * NPB + j];
            z[i] = fmaf(x[i], nw[i], fmaf(dis[i], a, b0));
        }
    }
}

__global__ void k_pairs(const float* __restrict__ z, const int* __restrict__ home,
                        const int* __restrict__ away, float* __restrict__ out, int n) {
    int i = blockIdx.x * blockDim.x + threadIdx.x;
    if (i < n) {
        float d = z[home[i]] - z[away[i]];
        out[i] = (d > 0.0f) ? 1.0f : ((d < 0.0f) ? -1.0f : 0.0f);
    }
}

// ---- fallback (device atomics) --------------------------------------------

__global__ void f_degree(const int* __restrict__ col, int* __restrict__ deg, int e4) {
    int i = blockIdx.x * blockDim.x + threadIdx.x;
    int stride = gridDim.x * blockDim.x;
    const int4* c4 = (const int4*)col;
    for (; i < e4; i += stride) {
        int4 c = c4[i];
        atomicAdd(&deg[c.x], 1); atomicAdd(&deg[c.y], 1);
        atomicAdd(&deg[c.z], 1); atomicAdd(&deg[c.w], 1);
    }
}
__global__ void f_dis(unsigned* __restrict__ degdis, const float* __restrict__ x,
                      float* __restrict__ px, int n) {
    int i = blockIdx.x * blockDim.x + threadIdx.x;
    int stride = gridDim.x * blockDim.x;
    float* disf = (float*)degdis;
    for (; i < n; i += stride) {
        unsigned d = degdis[i];
        float v = (d > 0u) ? rsqrtf((float)d) : 0.0f;
        disf[i] = v;
        px[i] = v * x[i];
    }
}
__global__ void f_scatter(const int* __restrict__ row, const int* __restrict__ col,
                          const float* __restrict__ px, float* __restrict__ agg, int e4) {
    int i = blockIdx.x * blockDim.x + threadIdx.x;
    int stride = gridDim.x * blockDim.x;
    const int4* r4 = (const int4*)row;
    const int4* c4 = (const int4*)col;
    for (; i < e4; i += stride) {
        int4 r = r4[i];
        int4 c = c4[i];
        atomicAdd(&agg[c.x], px[r.x]); atomicAdd(&agg[c.y], px[r.y]);
        atomicAdd(&agg[c.z], px[r.z]); atomicAdd(&agg[c.w], px[r.w]);
    }
}
__global__ void f_z(const float* __restrict__ x, const float* __restrict__ nw,
                    const float* __restrict__ dis, const float* __restrict__ bias,
                    float* __restrict__ agg, int n) {
    int i = blockIdx.x * blockDim.x + threadIdx.x;
    int stride = gridDim.x * blockDim.x;
    float b = bias[0];
    for (; i < n; i += stride)
        agg[i] = fmaf(x[i], nw[i], fmaf(dis[i], agg[i], b));
}

// ---------------------------------------------------------------------------

extern "C" void kernel_launch(void* const* d_in, const int* in_sizes, int n_in,
                              void* d_out, int out_size, void* d_ws, size_t ws_size,
                              hipStream_t stream) {
    const float* x    = (const float*)d_in[0];
    const float* nw   = (const float*)d_in[1];
    const float* bias = (const float*)d_in[2];
    const int*   ei   = (const int*)d_in[3];
    const int*   home = (const int*)d_in[4];
    const int*   away = (const int*)d_in[5];
    float* out = (float*)d_out;

    const int N = in_sizes[0];          // 500000
    const int E = in_sizes[3] / 2;      // 16000000
    const int P = in_sizes[4];          // 100000

    const int* row = ei;
    const int* col = ei + E;

    const int NB  = (N + NPB - 1) >> NPB_SHIFT;           // 245
    const int cpb = (((E + GB - 1) / GB) + 3) & ~3;       // mult of 4

    auto align256 = [](size_t v) { return (v + 255) & ~(size_t)255; };
    size_t off = 0;
    size_t o_counts = off; off += align256((size_t)NBMAX * GB * 4);      // 1 MB
    size_t o_rowsum = off; off += align256(NBMAX * 4);
    size_t o_rowbas = off; off += align256(NBMAX * 4);
    size_t o_dis    = off; off += align256((size_t)N * 4);
    size_t o_px     = off; off += align256((size_t)N * 4);
    size_t o_z      = off; off += align256((size_t)N * 4);
    size_t o_part   = off; off += align256((size_t)NB * SSPLIT * NPB * 4); // 16 MB (pcnt/pacc shared)
    size_t o_pack   = off; off += align256((size_t)E * 4);               // 64 MB
    size_t need = off;

    bool fast = (NB <= NBMAX) && ((size_t)N <= (1u << (32 - NPB_SHIFT)))
                && (ws_size >= need);

    if (fast) {
        char* base = (char*)d_ws;
        unsigned* counts  = (unsigned*)(base + o_counts);
        unsigned* rowsum  = (unsigned*)(base + o_rowsum);
        unsigned* rowbase = (unsigned*)(base + o_rowbas);
        float*    dis     = (float*)(base + o_dis);
        float*    px      = (float*)(base + o_px);
        float*    z       = (float*)(base + o_z);
        unsigned* part    = (unsigned*)(base + o_part);   // pcnt, then reused as pacc
        unsigned* packed  = (unsigned*)(base + o_pack);

        k_hist<<<GB, TEDGE, 0, stream>>>(col, counts, E, cpb, NB);
        k_scanA<<<NB, 256, 0, stream>>>(counts, rowsum);
        k_scanB<<<1, 256, 0, stream>>>(rowsum, rowbase, NB);
        k_bin<<<GB, TBIN, 0, stream>>>(row, col, counts, rowbase, packed, E, cpb, NB);
        k_deg_slice<<<NB * SSPLIT, TSL, 0, stream>>>(packed, rowbase, part, E, NB);
        k_dis<<<NB, TMERGE, 0, stream>>>(part, x, dis, px, N, NB);
        k_scatter_slice<<<NB * SSPLIT, TSL, 0, stream>>>(packed, px, rowbase,
                                                         (float*)part, E, NB);
        k_z<<<NB, TMERGE, 0, stream>>>((const float*)part, x, nw, dis, bias, z, N, NB);
        k_pairs<<<(P + 255) / 256, 256, 0, stream>>>(z, home, away, out, P);
    } else {
        size_t slot = align256((size_t)N * 4);
        int*   deg = (int*)d_ws;
        float* agg = (float*)((char*)d_ws + slot);
        float* px  = (float*)((char*)d_ws + 2 * slot);
        const int e4 = E / 4;
        hipMemsetAsync(d_ws, 0, 2 * slot, stream);
        f_degree<<<2048, 256, 0, stream>>>(col, deg, e4);
        f_dis<<<2048, 256, 0, stream>>>((unsigned*)deg, x, px, N);
        f_scatter<<<2048, 256, 0, stream>>>(row, col, px, agg, e4);
        f_z<<<2048, 256, 0, stream>>>(x, nw, (const float*)deg, bias, agg, N);
        k_pairs<<<(P + 255) / 256, 256, 0, stream>>>(agg, home, away, out, P);
    }
}